// Round 5
// baseline (240.930 us; speedup 1.0000x reference)
//
#include <hip/hip_runtime.h>
#include <hip/hip_cooperative_groups.h>
#include <math.h>

namespace cg = cooperative_groups;

#define T_DIM 512
#define B_DIM 64
#define D_DIM 256
#define F_DIM 256
#define ALPHA 0.2f
#define L2E 1.44269504089f
#define NEGL -1.0e38f

// workspace layout (floats). Every slot consumed is written the same call.
#define U_OFF 0
#define V_OFF 256
#define P_OFF 512
#define Q_OFF (P_OFF + T_DIM * B_DIM)
#define GG_OFF (Q_OFF + T_DIM * B_DIM)             // gg[3][B][T]
#define ZP_OFF (GG_OFF + 3 * B_DIM * T_DIM)        // Zp[B][16][D]

// ---------- Phase 0: u = W@a1, v = W@a2 (one wave per d) ----------
__device__ __forceinline__ void ph_uv(int bi, int tid, const float* __restrict__ W,
                                      const float* __restrict__ a1,
                                      const float* __restrict__ a2,
                                      float* __restrict__ ws) {
    int gw = bi * 8 + (tid >> 6);
    if (gw < D_DIM) {
        int lane = tid & 63;
        float4 wv = ((const float4*)(W + (size_t)gw * F_DIM))[lane];
        float4 a1v = ((const float4*)a1)[lane];
        float4 a2v = ((const float4*)a2)[lane];
        float p = wv.x * a1v.x + wv.y * a1v.y + wv.z * a1v.z + wv.w * a1v.w;
        float q = wv.x * a2v.x + wv.y * a2v.y + wv.z * a2v.z + wv.w * a2v.w;
        for (int off = 32; off > 0; off >>= 1) {
            p += __shfl_down(p, off);
            q += __shfl_down(q, off);
        }
        if (lane == 0) {
            ws[U_OFF + gw] = p;
            ws[V_OFF + gw] = q;
        }
    }
}

// ---------- Phase 1: p[b,t]=x[t,b]·u, q[b,t]=x[t,b]·v (8 rows per wave) ----------
__device__ __forceinline__ void ph_pq(int bi, int tid, const float* __restrict__ x,
                                      const int* __restrict__ turns,
                                      float* __restrict__ ws) {
    __shared__ float su[D_DIM], sv[D_DIM];
    if (tid < 64) ((float4*)su)[tid] = ((const float4*)(ws + U_OFF))[tid];
    else if (tid < 128) ((float4*)sv)[tid - 64] = ((const float4*)(ws + V_OFF))[tid - 64];
    __syncthreads();
    int lane = tid & 63;
    int gw = bi * 8 + (tid >> 6);         // [0, 4096)
    int b = gw & 63;                      // 4096 % 64 == 0 -> b constant over k
    int tbase = gw >> 6;
    int tn = turns[b];
    const float4* u4 = (const float4*)su;
    const float4* v4 = (const float4*)sv;
    float4 uv = u4[lane], vv = v4[lane];
#pragma unroll
    for (int k = 0; k < 8; ++k) {
        int t = tbase + k * 64;
        if (t <= tn) {                    // wave-uniform
            size_t r = (size_t)t * B_DIM + b;
            float4 xv = ((const float4*)x)[r * (D_DIM / 4) + lane];
            float pp = xv.x * uv.x + xv.y * uv.y + xv.z * uv.z + xv.w * uv.w;
            float qq = xv.x * vv.x + xv.y * vv.y + xv.z * vv.z + xv.w * vv.w;
            for (int off = 32; off > 0; off >>= 1) {
                pp += __shfl_down(pp, off);
                qq += __shfl_down(qq, off);
            }
            if (lane == 0) {
                ws[P_OFF + b * T_DIM + t] = pp;
                ws[Q_OFF + b * T_DIM + t] = qq;
            }
        }
    }
}

// ---------- Phase 2: fused attention row+col pass, one block per (b,w) ----------
__device__ __forceinline__ void ph_attn(int bi, int tid, const int* __restrict__ turns,
                                        float* __restrict__ ws) {
    if (bi >= 192) return;                 // function-local return (no grid.sync inside)
    int b = bi / 3, w = bi % 3 + 1;
    int tn = turns[b];
    int cnt = tn - w + 2;
    if (cnt > T_DIM) cnt = T_DIM;
    float* GG = ws + GG_OFF + ((w - 1) * B_DIM + b) * T_DIM;
    if (cnt <= 0) {                        // block-uniform
        GG[tid] = 0.f;
        return;
    }
    __shared__ float sp[T_DIM], sq[T_DIM], f2L[T_DIM], red[8];
    __shared__ float2 fc[T_DIM];
    if (tid < 128) {
        ((float4*)sp)[tid] = ((const float4*)(ws + P_OFF + b * T_DIM))[tid];
        ((float4*)sq)[tid] = ((const float4*)(ws + Q_OFF + b * T_DIM))[tid];
    }
    __syncthreads();
    float scale = L2E / (float)w;
    int j = tid;
    float vj;
    if (j < cnt) {
        float a = sq[j];
        if (w > 1) a += sq[j + 1];         // j+w-1 <= tn <= 511
        if (w > 2) a += sq[j + 2];
        vj = a * scale;
    } else {
        vj = NEGL;
    }
    f2L[j] = vj;
    float m = vj;
    for (int off = 32; off > 0; off >>= 1) m = fmaxf(m, __shfl_down(m, off));
    if ((tid & 63) == 0) red[tid >> 6] = m;
    __syncthreads();                       // covers f2L + red
    float M = red[0];
#pragma unroll
    for (int i2 = 1; i2 < 8; ++i2) M = fmaxf(M, red[i2]);
    if (j < cnt) {
        float a = sp[j];
        if (w > 1) a += sp[j + 1];
        if (w > 2) a += sp[j + 2];
        float f1 = a * scale;
        float s0 = f1 + M;
        float mrow = fmaxf(s0, ALPHA * s0);  // analytic row max (lrelu monotone)
        float r = 0.f;
        for (int jj = 0; jj < cnt; ++jj) {
            float s = f1 + f2L[jj];
            s = fmaxf(s, ALPHA * s);
            r += __builtin_amdgcn_exp2f(s - mrow);
        }
        fc[j] = make_float2(f1, mrow + __builtin_amdgcn_logf(r));  // log2
    }
    __syncthreads();
    float acc = 0.f;
    if (j < cnt) {
        for (int i = 0; i < cnt; ++i) {
            float2 t2 = fc[i];
            float s = t2.x + vj;
            s = fmaxf(s, ALPHA * s);
            acc += __builtin_amdgcn_exp2f(s - t2.y);
        }
        acc /= (float)cnt;
    }
    GG[j] = (j < cnt) ? acc : 0.f;
}

// ---------- Phase 3: Zp[b][chunk][d] = sum_{t in chunk} C[b,t]*x[t,b,d] ----------
__device__ __forceinline__ void ph_z(int bi, int tid, const float* __restrict__ x,
                                     const int* __restrict__ turns,
                                     float* __restrict__ ws) {
    __shared__ float Cs[64];
    __shared__ float4 zp[512];
    int b = bi >> 3, cp = bi & 7;
    int half = tid >> 8, tid2 = tid & 255;
    int chunk = cp * 2 + half;
    int tn = turns[b];
    int t0b = chunk * 32;
    if (tid2 < 32) {
        int t = t0b + tid2;
        const float* G1 = ws + GG_OFF + (0 * B_DIM + b) * T_DIM;
        const float* G2 = ws + GG_OFF + (1 * B_DIM + b) * T_DIM;
        const float* G3 = ws + GG_OFF + (2 * B_DIM + b) * T_DIM;
        float g2 = G2[t] + (t >= 1 ? G2[t - 1] : 0.f);
        float g3 = G3[t] + (t >= 1 ? G3[t - 1] : 0.f) + (t >= 2 ? G3[t - 2] : 0.f);
        Cs[half * 32 + tid2] = G1[t] + 0.5f * g2 + (1.0f / 3.0f) * g3;
    }
    __syncthreads();
    float4 z = make_float4(0.f, 0.f, 0.f, 0.f);
    if (t0b <= tn) {                       // wave-uniform (half-uniform)
        int g = tid2 >> 6, lane = tid2 & 63;
        int tg = t0b + g * 8;
        size_t base = ((size_t)tg * B_DIM + b) * (D_DIM / 4) + lane;
#pragma unroll
        for (int tt = 0; tt < 8; ++tt) {
            float c = Cs[half * 32 + g * 8 + tt];
            float4 xv = ((const float4*)x)[base + (size_t)tt * (B_DIM * D_DIM / 4)];
            z.x += c * xv.x; z.y += c * xv.y; z.z += c * xv.z; z.w += c * xv.w;
        }
    }
    zp[tid] = z;
    __syncthreads();
    if (tid2 < 64) {
        int base = half * 256;
        float4 a = zp[base + tid2];
        float4 b1 = zp[base + 64 + tid2], c1 = zp[base + 128 + tid2], d1 = zp[base + 192 + tid2];
        a.x += b1.x + c1.x + d1.x;
        a.y += b1.y + c1.y + d1.y;
        a.z += b1.z + c1.z + d1.z;
        a.w += b1.w + c1.w + d1.w;
        ((float4*)(ws + ZP_OFF + (size_t)(b * 16 + chunk) * D_DIM))[tid2] = a;
    }
}

// ---------- Phase 4: out[b,:] = ((sum_chunk Zp) @ W) / vws ----------
__device__ __forceinline__ void ph_out(int bi, int tid, const float* __restrict__ W,
                                       const int* __restrict__ turns,
                                       const float* __restrict__ ws,
                                       float* __restrict__ out) {
    if (bi >= B_DIM) return;
    int b = bi;
    __shared__ float zhalf[2][D_DIM];
    __shared__ float zz[D_DIM];
    __shared__ float ored[512];
    int half = tid >> 8, d = tid & 255;
    const float* Zp = ws + ZP_OFF + (size_t)b * 16 * D_DIM;
    float a = 0.f;
#pragma unroll
    for (int s = 0; s < 8; ++s) a += Zp[(half * 8 + s) * D_DIM + d];
    zhalf[half][d] = a;
    __syncthreads();
    if (tid < 256) zz[tid] = zhalf[0][tid] + zhalf[1][tid];
    __syncthreads();
    int f = tid & 255, dh = tid >> 8;
    float acc = 0.f;
#pragma unroll 8
    for (int dd = dh * 128; dd < dh * 128 + 128; ++dd)
        acc += zz[dd] * W[(size_t)dd * F_DIM + f];
    ored[tid] = acc;
    __syncthreads();
    if (tid < 256) {
        int tn = turns[b];
        float vws = 1.f + (tn >= 1 ? 1.f : 0.f) + (tn >= 2 ? 1.f : 0.f);
        out[b * F_DIM + tid] = (ored[tid] + ored[tid + 256]) / vws;
    }
}

// ---------- Cooperative mega-kernel ----------
__global__ __launch_bounds__(512, 4) void mega(const float* __restrict__ x,
                                               const int* __restrict__ turns,
                                               const float* __restrict__ W,
                                               const float* __restrict__ a1,
                                               const float* __restrict__ a2,
                                               float* __restrict__ out,
                                               float* __restrict__ ws) {
    cg::grid_group grid = cg::this_grid();
    int bi = blockIdx.x, tid = threadIdx.x;
    ph_uv(bi, tid, W, a1, a2, ws);
    grid.sync();
    ph_pq(bi, tid, x, turns, ws);
    grid.sync();
    ph_attn(bi, tid, turns, ws);
    grid.sync();
    ph_z(bi, tid, x, turns, ws);
    grid.sync();
    ph_out(bi, tid, W, turns, ws, out);
}

// ---------- Fallback wrappers (same phase fns, same grid mapping) ----------
__global__ __launch_bounds__(512) void g_uv(const float* W, const float* a1,
                                            const float* a2, float* ws) {
    ph_uv(blockIdx.x, threadIdx.x, W, a1, a2, ws);
}
__global__ __launch_bounds__(512) void g_pq(const float* x, const int* turns, float* ws) {
    ph_pq(blockIdx.x, threadIdx.x, x, turns, ws);
}
__global__ __launch_bounds__(512) void g_attn(const int* turns, float* ws) {
    ph_attn(blockIdx.x, threadIdx.x, turns, ws);
}
__global__ __launch_bounds__(512) void g_z(const float* x, const int* turns, float* ws) {
    ph_z(blockIdx.x, threadIdx.x, x, turns, ws);
}
__global__ __launch_bounds__(512) void g_out(const float* W, const int* turns,
                                             const float* ws, float* out) {
    ph_out(blockIdx.x, threadIdx.x, W, turns, ws, out);
}

extern "C" void kernel_launch(void* const* d_in, const int* in_sizes, int n_in,
                              void* d_out, int out_size, void* d_ws, size_t ws_size,
                              hipStream_t stream) {
    const float* x = (const float*)d_in[0];     // (T,B,D) fp32
    const int* turns = (const int*)d_in[1];     // (B,) int32
    const float* W = (const float*)d_in[2];     // (D,F)
    const float* a1 = (const float*)d_in[3];    // (F,)
    const float* a2 = (const float*)d_in[4];    // (F,)
    float* out = (float*)d_out;                 // (B,F)
    float* ws = (float*)d_ws;

    void* args[] = {(void*)&x, (void*)&turns, (void*)&W, (void*)&a1,
                    (void*)&a2, (void*)&out, (void*)&ws};
    hipError_t e = hipLaunchCooperativeKernel((const void*)mega, dim3(512), dim3(512),
                                              args, 0, stream);
    if (e != hipSuccess) {
        // deterministic fallback: same phases as separate graph nodes
        g_uv<<<512, 512, 0, stream>>>(W, a1, a2, ws);
        g_pq<<<512, 512, 0, stream>>>(x, turns, ws);
        g_attn<<<512, 512, 0, stream>>>(turns, ws);
        g_z<<<512, 512, 0, stream>>>(x, turns, ws);
        g_out<<<512, 512, 0, stream>>>(W, turns, ws, out);
    }
}

// Round 6
// 55.093 us; speedup vs baseline: 4.3731x; 4.3731x over previous
//
#include <hip/hip_runtime.h>
#include <math.h>

#define T_DIM 512
#define B_DIM 64
#define D_DIM 256
#define F_DIM 256
#define ALPHA 0.2f
#define L2E 1.44269504089f
#define NEGL -1.0e38f

// workspace layout (floats). Every slot consumed is written the same call.
#define U_OFF 0
#define V_OFF 256
#define P_OFF 512
#define Q_OFF (P_OFF + T_DIM * B_DIM)
#define GG_OFF (Q_OFF + T_DIM * B_DIM)             // gg[3][B][T]

// ---------- Node 1: u = W@a1, v = W@a2. 64 blocks x 256 thr ----------
__global__ __launch_bounds__(256) void g_uv(const float* __restrict__ W,
                                            const float* __restrict__ a1,
                                            const float* __restrict__ a2,
                                            float* __restrict__ ws) {
    int tid = threadIdx.x;
    int wave = tid >> 6, lane = tid & 63;
    int d = blockIdx.x * 4 + wave;
    float4 wv = ((const float4*)(W + (size_t)d * F_DIM))[lane];
    float4 a1v = ((const float4*)a1)[lane];
    float4 a2v = ((const float4*)a2)[lane];
    float p = wv.x * a1v.x + wv.y * a1v.y + wv.z * a1v.z + wv.w * a1v.w;
    float q = wv.x * a2v.x + wv.y * a2v.y + wv.z * a2v.z + wv.w * a2v.w;
    for (int off = 32; off > 0; off >>= 1) {
        p += __shfl_down(p, off);
        q += __shfl_down(q, off);
    }
    if (lane == 0) {
        ws[U_OFF + d] = p;
        ws[V_OFF + d] = q;
    }
}

// ---------- Node 2: p[b,t]=x[t,b]·u, q[b,t]=x[t,b]·v. 512 blocks x 512 thr ----------
__global__ __launch_bounds__(512) void g_pq(const float* __restrict__ x,
                                            const int* __restrict__ turns,
                                            float* __restrict__ ws) {
    __shared__ float su[D_DIM], sv[D_DIM];
    int tid = threadIdx.x;
    if (tid < 64) ((float4*)su)[tid] = ((const float4*)(ws + U_OFF))[tid];
    else if (tid < 128) ((float4*)sv)[tid - 64] = ((const float4*)(ws + V_OFF))[tid - 64];
    __syncthreads();
    int lane = tid & 63;
    int gw = blockIdx.x * 8 + (tid >> 6);  // [0, 4096)
    int b = gw & 63;
    int tbase = gw >> 6;
    int tn = turns[b];
    const float4* u4 = (const float4*)su;
    const float4* v4 = (const float4*)sv;
    float4 uv = u4[lane], vv = v4[lane];
#pragma unroll
    for (int k = 0; k < 8; ++k) {
        int t = tbase + k * 64;
        if (t <= tn) {                    // wave-uniform
            size_t r = (size_t)t * B_DIM + b;
            float4 xv = ((const float4*)x)[r * (D_DIM / 4) + lane];
            float pp = xv.x * uv.x + xv.y * uv.y + xv.z * uv.z + xv.w * uv.w;
            float qq = xv.x * vv.x + xv.y * vv.y + xv.z * vv.z + xv.w * vv.w;
            for (int off = 32; off > 0; off >>= 1) {
                pp += __shfl_down(pp, off);
                qq += __shfl_down(qq, off);
            }
            if (lane == 0) {
                ws[P_OFF + b * T_DIM + t] = pp;
                ws[Q_OFF + b * T_DIM + t] = qq;
            }
        }
    }
}

// ---------- Node 3: fused attention row+col per (b,w); also zeroes d_out ----------
// 192 blocks x 512 threads.
__global__ __launch_bounds__(512) void g_attn(const int* __restrict__ turns,
                                              float* __restrict__ ws,
                                              float* __restrict__ out) {
    int bi = blockIdx.x, tid = threadIdx.x;
    if (bi < 32) out[bi * 512 + tid] = 0.f;   // zero d_out for Node 4 atomics
    int b = bi / 3, w = bi % 3 + 1;
    int tn = turns[b];
    int cnt = tn - w + 2;
    if (cnt > T_DIM) cnt = T_DIM;
    float* GG = ws + GG_OFF + ((w - 1) * B_DIM + b) * T_DIM;
    if (cnt <= 0) {                        // block-uniform
        GG[tid] = 0.f;
        return;
    }
    __shared__ float sp[T_DIM], sq[T_DIM], f2L[T_DIM], red[8];
    __shared__ float2 fc[T_DIM];
    if (tid < 128) {
        ((float4*)sp)[tid] = ((const float4*)(ws + P_OFF + b * T_DIM))[tid];
        ((float4*)sq)[tid] = ((const float4*)(ws + Q_OFF + b * T_DIM))[tid];
    }
    __syncthreads();
    float scale = L2E / (float)w;
    int j = tid;
    float vj;
    if (j < cnt) {
        float a = sq[j];
        if (w > 1) a += sq[j + 1];         // j+w-1 <= tn <= 511, k_pq-written
        if (w > 2) a += sq[j + 2];
        vj = a * scale;
    } else {
        vj = NEGL;
    }
    f2L[j] = vj;
    float m = vj;
    for (int off = 32; off > 0; off >>= 1) m = fmaxf(m, __shfl_down(m, off));
    if ((tid & 63) == 0) red[tid >> 6] = m;
    __syncthreads();                       // covers f2L + red
    float M = red[0];
#pragma unroll
    for (int i2 = 1; i2 < 8; ++i2) M = fmaxf(M, red[i2]);
    if (j < cnt) {
        float a = sp[j];
        if (w > 1) a += sp[j + 1];
        if (w > 2) a += sp[j + 2];
        float f1 = a * scale;
        float s0 = f1 + M;
        float mrow = fmaxf(s0, ALPHA * s0);  // analytic row max (lrelu monotone)
        float r = 0.f;
        for (int jj = 0; jj < cnt; ++jj) {
            float s = f1 + f2L[jj];
            s = fmaxf(s, ALPHA * s);
            r += __builtin_amdgcn_exp2f(s - mrow);
        }
        fc[j] = make_float2(f1, mrow + __builtin_amdgcn_logf(r));  // log2 domain
    }
    __syncthreads();
    float acc = 0.f;
    if (j < cnt) {
        for (int i = 0; i < cnt; ++i) {
            float2 t2 = fc[i];
            float s = t2.x + vj;
            s = fmaxf(s, ALPHA * s);
            acc += __builtin_amdgcn_exp2f(s - t2.y);
        }
        acc /= (float)cnt;
    }
    GG[j] = (j < cnt) ? acc : 0.f;
}

// ---------- Node 4: fused Z + GEMV -> atomicAdd out ----------
// 256 blocks (64 b x 4 chunks of 128 t) x 512 threads.
__global__ __launch_bounds__(512) void g_zout(const float* __restrict__ x,
                                              const int* __restrict__ turns,
                                              const float* __restrict__ W,
                                              const float* __restrict__ ws,
                                              float* __restrict__ out) {
    int b = blockIdx.x >> 2;
    int chunk = blockIdx.x & 3;
    int tn = turns[b];
    int t0 = chunk * 128;
    if (t0 > tn) return;                   // zero contribution (block-uniform)
    int tid = threadIdx.x;
    __shared__ float Cs[128];
    __shared__ float4 zp[512];
    __shared__ float Zs[D_DIM];
    __shared__ float ored[512];
    if (tid < 128) {
        int t = t0 + tid;
        const float* G1 = ws + GG_OFF + (0 * B_DIM + b) * T_DIM;
        const float* G2 = ws + GG_OFF + (1 * B_DIM + b) * T_DIM;
        const float* G3 = ws + GG_OFF + (2 * B_DIM + b) * T_DIM;
        // GG is zero beyond each window's cnt -> C[t]=0 for t>tn automatically.
        float g2 = G2[t] + (t >= 1 ? G2[t - 1] : 0.f);
        float g3 = G3[t] + (t >= 1 ? G3[t - 1] : 0.f) + (t >= 2 ? G3[t - 2] : 0.f);
        float vws = 1.f + (tn >= 1 ? 1.f : 0.f) + (tn >= 2 ? 1.f : 0.f);
        Cs[tid] = (G1[t] + 0.5f * g2 + (1.0f / 3.0f) * g3) / vws;
    }
    __syncthreads();
    int wave = tid >> 6, lane = tid & 63;
    float4 z = make_float4(0.f, 0.f, 0.f, 0.f);
    {
        int tg = t0 + wave * 16;
        size_t base = ((size_t)tg * B_DIM + b) * (D_DIM / 4) + lane;
#pragma unroll 8
        for (int tt = 0; tt < 16; ++tt) {
            float c = Cs[wave * 16 + tt];
            float4 xv = ((const float4*)x)[base + (size_t)tt * (B_DIM * D_DIM / 4)];
            z.x += c * xv.x; z.y += c * xv.y; z.z += c * xv.z; z.w += c * xv.w;
        }
    }
    zp[tid] = z;
    __syncthreads();
    if (tid < 64) {
        float4 a = zp[tid];
#pragma unroll
        for (int k = 1; k < 8; ++k) {
            float4 bb = zp[k * 64 + tid];
            a.x += bb.x; a.y += bb.y; a.z += bb.z; a.w += bb.w;
        }
        ((float4*)Zs)[tid] = a;
    }
    __syncthreads();
    int f = tid & 255, dh = tid >> 8;
    float acc = 0.f;
#pragma unroll 8
    for (int dd = dh * 128; dd < dh * 128 + 128; ++dd)
        acc += Zs[dd] * W[(size_t)dd * F_DIM + f];
    ored[tid] = acc;
    __syncthreads();
    if (tid < 256)
        atomicAdd(&out[b * F_DIM + tid], ored[tid] + ored[tid + 256]);
}

extern "C" void kernel_launch(void* const* d_in, const int* in_sizes, int n_in,
                              void* d_out, int out_size, void* d_ws, size_t ws_size,
                              hipStream_t stream) {
    const float* x = (const float*)d_in[0];     // (T,B,D) fp32
    const int* turns = (const int*)d_in[1];     // (B,) int32
    const float* W = (const float*)d_in[2];     // (D,F)
    const float* a1 = (const float*)d_in[3];    // (F,)
    const float* a2 = (const float*)d_in[4];    // (F,)
    float* out = (float*)d_out;                 // (B,F)
    float* ws = (float*)d_ws;

    g_uv<<<B_DIM, 256, 0, stream>>>(W, a1, a2, ws);
    g_pq<<<512, 512, 0, stream>>>(x, turns, ws);
    g_attn<<<B_DIM * 3, 512, 0, stream>>>(turns, ws, out);
    g_zout<<<B_DIM * 4, 512, 0, stream>>>(x, turns, W, ws, out);
}

// Round 7
// 53.491 us; speedup vs baseline: 4.5041x; 1.0299x over previous
//
#include <hip/hip_runtime.h>
#include <math.h>

#define T_DIM 512
#define B_DIM 64
#define D_DIM 256
#define F_DIM 256
#define ALPHA 0.2f
#define L2E 1.44269504089f
#define NEGL -1.0e38f

// workspace layout (floats). Every slot consumed is zeroed/written the same call.
#define U_OFF 0
#define V_OFF 256
#define P_OFF 512
#define Q_OFF (P_OFF + T_DIM * B_DIM)
#define GG_OFF (Q_OFF + T_DIM * B_DIM)             // gg[3][B][T] (atomic)
#define R_OFF (GG_OFF + 3 * B_DIM * T_DIM)         // r [3][B][T] (atomic)

// ---------- Node 1: u = W@a1, v = W@a2; zero R. 64 blocks x 256 thr ----------
__global__ __launch_bounds__(256) void g_uv(const float* __restrict__ W,
                                            const float* __restrict__ a1,
                                            const float* __restrict__ a2,
                                            float* __restrict__ ws) {
    int tid = threadIdx.x;
    int gid = blockIdx.x * 256 + tid;
#pragma unroll
    for (int k = 0; k < 6; ++k)                    // 6*16384 == 3*B*T
        ws[R_OFF + k * 16384 + gid] = 0.f;
    int wave = tid >> 6, lane = tid & 63;
    int d = blockIdx.x * 4 + wave;
    float4 wv = ((const float4*)(W + (size_t)d * F_DIM))[lane];
    float4 a1v = ((const float4*)a1)[lane];
    float4 a2v = ((const float4*)a2)[lane];
    float p = wv.x * a1v.x + wv.y * a1v.y + wv.z * a1v.z + wv.w * a1v.w;
    float q = wv.x * a2v.x + wv.y * a2v.y + wv.z * a2v.z + wv.w * a2v.w;
    for (int off = 32; off > 0; off >>= 1) {
        p += __shfl_down(p, off);
        q += __shfl_down(q, off);
    }
    if (lane == 0) {
        ws[U_OFF + d] = p;
        ws[V_OFF + d] = q;
    }
}

// ---------- Node 2: p,q dot products; zero GG. 512 blocks x 512 thr ----------
__global__ __launch_bounds__(512) void g_pq(const float* __restrict__ x,
                                            const int* __restrict__ turns,
                                            float* __restrict__ ws) {
    __shared__ float su[D_DIM], sv[D_DIM];
    int tid = threadIdx.x;
    int gid = blockIdx.x * 512 + tid;
    if (gid < 3 * B_DIM * T_DIM) ws[GG_OFF + gid] = 0.f;
    if (tid < 64) ((float4*)su)[tid] = ((const float4*)(ws + U_OFF))[tid];
    else if (tid < 128) ((float4*)sv)[tid - 64] = ((const float4*)(ws + V_OFF))[tid - 64];
    __syncthreads();
    int lane = tid & 63;
    int gw = blockIdx.x * 8 + (tid >> 6);  // [0, 4096)
    int b = gw & 63;
    int tbase = gw >> 6;
    int tn = turns[b];
    const float4* u4 = (const float4*)su;
    const float4* v4 = (const float4*)sv;
    float4 uv = u4[lane], vv = v4[lane];
#pragma unroll
    for (int k = 0; k < 8; ++k) {
        int t = tbase + k * 64;
        if (t <= tn) {                    // wave-uniform
            size_t r = (size_t)t * B_DIM + b;
            float4 xv = ((const float4*)x)[r * (D_DIM / 4) + lane];
            float pp = xv.x * uv.x + xv.y * uv.y + xv.z * uv.z + xv.w * uv.w;
            float qq = xv.x * vv.x + xv.y * vv.y + xv.z * vv.z + xv.w * vv.w;
            for (int off = 32; off > 0; off >>= 1) {
                pp += __shfl_down(pp, off);
                qq += __shfl_down(qq, off);
            }
            if (lane == 0) {
                ws[P_OFF + b * T_DIM + t] = pp;
                ws[Q_OFF + b * T_DIM + t] = qq;
            }
        }
    }
}

// ---------- Node 3: balanced row pass. 768 blocks (b,w,jchunk) x 512 thr ----------
// r_i partial over j-chunk -> atomicAdd R. Also zeroes d_out.
__global__ __launch_bounds__(512) void g_row(const int* __restrict__ turns,
                                             float* __restrict__ ws,
                                             float* __restrict__ out) {
    int bi = blockIdx.x, tid = threadIdx.x;
    if (bi < 32) out[bi * 512 + tid] = 0.f;   // zero d_out for Node 5 atomics
    int b = bi / 12, rem = bi % 12;
    int w = (rem >> 2) + 1, jc = rem & 3;
    int tn = turns[b];
    int cnt = tn - w + 2;
    if (cnt > T_DIM) cnt = T_DIM;
    if (cnt <= 0) return;                      // block-uniform; R/GG stay 0
    int j0 = jc * 128;
    if (j0 >= cnt) return;                     // block-uniform
    __shared__ float sp[T_DIM], sq[T_DIM], f2L[T_DIM], red[8];
    if (tid < 128) {
        ((float4*)sp)[tid] = ((const float4*)(ws + P_OFF + b * T_DIM))[tid];
        ((float4*)sq)[tid] = ((const float4*)(ws + Q_OFF + b * T_DIM))[tid];
    }
    __syncthreads();
    float scale = L2E / (float)w;
    int j = tid;
    float vj;
    if (j < cnt) {
        float a = sq[j];
        if (w > 1) a += sq[j + 1];             // j+w-1 <= tn <= 511
        if (w > 2) a += sq[j + 2];
        vj = a * scale;
    } else {
        vj = NEGL;
    }
    f2L[j] = vj;
    float m = vj;
    for (int off = 32; off > 0; off >>= 1) m = fmaxf(m, __shfl_down(m, off));
    if ((tid & 63) == 0) red[tid >> 6] = m;
    __syncthreads();                           // covers f2L + red
    float M = red[0];
#pragma unroll
    for (int i2 = 1; i2 < 8; ++i2) M = fmaxf(M, red[i2]);
    if (tid < cnt) {
        float a = sp[tid];
        if (w > 1) a += sp[tid + 1];
        if (w > 2) a += sp[tid + 2];
        float f1 = a * scale;
        float s0 = f1 + M;
        float mrow = fmaxf(s0, ALPHA * s0);    // analytic row max (lrelu monotone)
        float r = 0.f;
        int j1 = min(j0 + 128, cnt);
        for (int k = j0; k < j1; ++k) {
            float s = f1 + f2L[k];
            s = fmaxf(s, ALPHA * s);
            r += __builtin_amdgcn_exp2f(s - mrow);
        }
        atomicAdd(&ws[R_OFF + ((w - 1) * B_DIM + b) * T_DIM + tid], r);
    }
}

// ---------- Node 4: balanced col pass. 768 blocks (b,w,ichunk) x 512 thr ----------
// gg_j partial over i-chunk -> atomicAdd GG.
__global__ __launch_bounds__(512) void g_col(const int* __restrict__ turns,
                                             float* __restrict__ ws) {
    int bi = blockIdx.x, tid = threadIdx.x;
    int b = bi / 12, rem = bi % 12;
    int w = (rem >> 2) + 1, ic = rem & 3;
    int tn = turns[b];
    int cnt = tn - w + 2;
    if (cnt > T_DIM) cnt = T_DIM;
    if (cnt <= 0) return;                      // block-uniform
    int i0 = ic * 128;
    if (i0 >= cnt) return;                     // block-uniform
    __shared__ float sp[T_DIM], sq[T_DIM], red[8];
    __shared__ float2 fc[128];
    if (tid < 128) {
        ((float4*)sp)[tid] = ((const float4*)(ws + P_OFF + b * T_DIM))[tid];
        ((float4*)sq)[tid] = ((const float4*)(ws + Q_OFF + b * T_DIM))[tid];
    }
    __syncthreads();
    float scale = L2E / (float)w;
    int j = tid;
    float vj;
    if (j < cnt) {
        float a = sq[j];
        if (w > 1) a += sq[j + 1];
        if (w > 2) a += sq[j + 2];
        vj = a * scale;
    } else {
        vj = NEGL;
    }
    float m = vj;                              // same reduce as g_row -> identical M
    for (int off = 32; off > 0; off >>= 1) m = fmaxf(m, __shfl_down(m, off));
    if ((tid & 63) == 0) red[tid >> 6] = m;
    __syncthreads();
    float M = red[0];
#pragma unroll
    for (int i2 = 1; i2 < 8; ++i2) M = fmaxf(M, red[i2]);
    if (tid < 128) {
        int i = i0 + tid;
        float2 v = make_float2(0.f, 0.f);
        if (i < cnt) {
            float a = sp[i];
            if (w > 1) a += sp[i + 1];
            if (w > 2) a += sp[i + 2];
            float f1 = a * scale;
            float s0 = f1 + M;
            float mrow = fmaxf(s0, ALPHA * s0);
            float ri = ws[R_OFF + ((w - 1) * B_DIM + b) * T_DIM + i];
            v = make_float2(f1, mrow + __builtin_amdgcn_logf(ri));  // log2 domain
        }
        fc[tid] = v;
    }
    __syncthreads();
    if (j < cnt) {
        float acc = 0.f;
        int ni = min(128, cnt - i0);
        for (int k = 0; k < ni; ++k) {
            float2 t2 = fc[k];
            float s = t2.x + vj;
            s = fmaxf(s, ALPHA * s);
            acc += __builtin_amdgcn_exp2f(s - t2.y);
        }
        atomicAdd(&ws[GG_OFF + ((w - 1) * B_DIM + b) * T_DIM + j], acc / (float)cnt);
    }
}

// ---------- Node 5: fused Z + GEMV -> atomicAdd out ----------
// 256 blocks (64 b x 4 chunks of 128 t) x 512 threads.
__global__ __launch_bounds__(512) void g_zout(const float* __restrict__ x,
                                              const int* __restrict__ turns,
                                              const float* __restrict__ W,
                                              const float* __restrict__ ws,
                                              float* __restrict__ out) {
    int b = blockIdx.x >> 2;
    int chunk = blockIdx.x & 3;
    int tn = turns[b];
    int t0 = chunk * 128;
    if (t0 > tn) return;                   // zero contribution (block-uniform)
    int tid = threadIdx.x;
    __shared__ float Cs[128];
    __shared__ float4 zp[512];
    __shared__ float Zs[D_DIM];
    __shared__ float ored[512];
    if (tid < 128) {
        int t = t0 + tid;
        const float* G1 = ws + GG_OFF + (0 * B_DIM + b) * T_DIM;
        const float* G2 = ws + GG_OFF + (1 * B_DIM + b) * T_DIM;
        const float* G3 = ws + GG_OFF + (2 * B_DIM + b) * T_DIM;
        // GG is zero beyond each window's cnt -> C[t]=0 for t>tn automatically.
        float g2 = G2[t] + (t >= 1 ? G2[t - 1] : 0.f);
        float g3 = G3[t] + (t >= 1 ? G3[t - 1] : 0.f) + (t >= 2 ? G3[t - 2] : 0.f);
        float vws = 1.f + (tn >= 1 ? 1.f : 0.f) + (tn >= 2 ? 1.f : 0.f);
        Cs[tid] = (G1[t] + 0.5f * g2 + (1.0f / 3.0f) * g3) / vws;
    }
    __syncthreads();
    int wave = tid >> 6, lane = tid & 63;
    float4 z = make_float4(0.f, 0.f, 0.f, 0.f);
    {
        int tg = t0 + wave * 16;
        size_t base = ((size_t)tg * B_DIM + b) * (D_DIM / 4) + lane;
#pragma unroll 8
        for (int tt = 0; tt < 16; ++tt) {
            float c = Cs[wave * 16 + tt];
            float4 xv = ((const float4*)x)[base + (size_t)tt * (B_DIM * D_DIM / 4)];
            z.x += c * xv.x; z.y += c * xv.y; z.z += c * xv.z; z.w += c * xv.w;
        }
    }
    zp[tid] = z;
    __syncthreads();
    if (tid < 64) {
        float4 a = zp[tid];
#pragma unroll
        for (int k = 1; k < 8; ++k) {
            float4 bb = zp[k * 64 + tid];
            a.x += bb.x; a.y += bb.y; a.z += bb.z; a.w += bb.w;
        }
        ((float4*)Zs)[tid] = a;
    }
    __syncthreads();
    int f = tid & 255, dh = tid >> 8;
    float acc = 0.f;
#pragma unroll 8
    for (int dd = dh * 128; dd < dh * 128 + 128; ++dd)
        acc += Zs[dd] * W[(size_t)dd * F_DIM + f];
    ored[tid] = acc;
    __syncthreads();
    if (tid < 256)
        atomicAdd(&out[b * F_DIM + tid], ored[tid] + ored[tid + 256]);
}

extern "C" void kernel_launch(void* const* d_in, const int* in_sizes, int n_in,
                              void* d_out, int out_size, void* d_ws, size_t ws_size,
                              hipStream_t stream) {
    const float* x = (const float*)d_in[0];     // (T,B,D) fp32
    const int* turns = (const int*)d_in[1];     // (B,) int32
    const float* W = (const float*)d_in[2];     // (D,F)
    const float* a1 = (const float*)d_in[3];    // (F,)
    const float* a2 = (const float*)d_in[4];    // (F,)
    float* out = (float*)d_out;                 // (B,F)
    float* ws = (float*)d_ws;

    g_uv<<<B_DIM, 256, 0, stream>>>(W, a1, a2, ws);
    g_pq<<<512, 512, 0, stream>>>(x, turns, ws);
    g_row<<<B_DIM * 12, 512, 0, stream>>>(turns, ws, out);
    g_col<<<B_DIM * 12, 512, 0, stream>>>(turns, ws);
    g_zout<<<B_DIM * 4, 512, 0, stream>>>(x, turns, W, ws, out);
}